// Round 8
// baseline (425.227 us; speedup 1.0000x reference)
//
#include <hip/hip_runtime.h>

// TargetModel_78786880077968: 2-layer GCN + mean pool
#define NN 100000      // nodes
#define NE 1600000     // edges
#define NG 512         // graphs
#define FD 64          // feature dim
#define NSL 4          // feature slices (XCD-pinned); 16 bf16 each = 32 B rows
#define CHUNK 128      // nodes per agg block
#define SCAN_CHUNK 1024
#define SCAN_BLOCKS 98                // ceil(NN / SCAN_CHUNK)
#define SR (NN + 1)                   // hs slice row stride (row NN = zeros)
#define COLCAP (NE + 15 * NN + 64)    // padded colidx capacity + spec-read guard

// ---- bf16 pack/unpack (RNE; values finite) ----
__device__ inline unsigned pack_bf16x2(float a, float b) {
    unsigned ua = __float_as_uint(a), ub = __float_as_uint(b);
    ua = (ua + 0x7FFFu + ((ua >> 16) & 1u)) >> 16;
    ub = (ub + 0x7FFFu + ((ub >> 16) & 1u)) >> 16;
    return ua | (ub << 16);
}
__device__ inline float bf_lo(unsigned u) { return __uint_as_float(u << 16); }
__device__ inline float bf_hi(unsigned u) { return __uint_as_float(u & 0xFFFF0000u); }

// ---------- init: colidx=NN (pad target), cnt=0, pool=0, hs zero-row ----------
__global__ void k_init(int* __restrict__ colidx, int* __restrict__ cnt,
                       float* __restrict__ pool, unsigned* __restrict__ hs) {
    int i = blockIdx.x * 256 + threadIdx.x;
    if (i < COLCAP / 4) {
        int4 v = {NN, NN, NN, NN};
        ((int4*)colidx)[i] = v;
    }
    if (i < NN / 4) {
        int4 z = {0, 0, 0, 0};
        ((int4*)cnt)[i] = z;
    }
    if (i < NSL * NG * 16 / 4) {
        float4 z = {0.f, 0.f, 0.f, 0.f};
        ((float4*)pool)[i] = z;
    }
    if (i < 8) {   // zero row NN of each hs slice (2 uint4 per 32 B row)
        uint4 z = {0u, 0u, 0u, 0u};
        ((uint4*)hs)[((size_t)(i >> 1) * SR + NN) * 2 + (i & 1)] = z;
    }
}

// ---------- CSR build ----------

__global__ void k_count_rank(const int* __restrict__ dst, int* __restrict__ cnt,
                             int* __restrict__ rank, int e) {
    int i = blockIdx.x * 256 + threadIdx.x;
    if (i < e) rank[i] = atomicAdd(&cnt[dst[i]], 1);
}

// exclusive scan over PADDED counts (round degree up to multiple of 16)
__global__ void k_scan1(const int* __restrict__ cnt, int* __restrict__ part,
                        int* __restrict__ blockSum, int n) {
    __shared__ int lds[256];
    int tid = threadIdx.x;
    int base = blockIdx.x * SCAN_CHUNK + tid * 4;
    int v0 = (base + 0 < n) ? (cnt[base + 0] + 15) & ~15 : 0;
    int v1 = (base + 1 < n) ? (cnt[base + 1] + 15) & ~15 : 0;
    int v2 = (base + 2 < n) ? (cnt[base + 2] + 15) & ~15 : 0;
    int v3 = (base + 3 < n) ? (cnt[base + 3] + 15) & ~15 : 0;
    int s = v0 + v1 + v2 + v3;
    lds[tid] = s;
    __syncthreads();
    for (int off = 1; off < 256; off <<= 1) {
        int t = (tid >= off) ? lds[tid - off] : 0;
        __syncthreads();
        lds[tid] += t;
        __syncthreads();
    }
    int run = lds[tid] - s;
    if (base + 0 < n) part[base + 0] = run; run += v0;
    if (base + 1 < n) part[base + 1] = run; run += v1;
    if (base + 2 < n) part[base + 2] = run; run += v2;
    if (base + 3 < n) part[base + 3] = run;
    if (tid == 255) blockSum[blockIdx.x] = lds[255];
}

__global__ void k_scan2(const int* __restrict__ bs, int* __restrict__ boff, int nb) {
    __shared__ int lds[128];
    int tid = threadIdx.x;
    int v = (tid < nb) ? bs[tid] : 0;
    lds[tid] = v;
    __syncthreads();
    for (int off = 1; off < 128; off <<= 1) {
        int t = (tid >= off) ? lds[tid - off] : 0;
        __syncthreads();
        lds[tid] += t;
        __syncthreads();
    }
    if (tid < nb) boff[tid] = lds[tid] - v;
}

__global__ void k_scan3(int* __restrict__ rowptr, const int* __restrict__ boff,
                        const int* __restrict__ cnt, float* __restrict__ dinv, int n) {
    int i = blockIdx.x * 256 + threadIdx.x;
    if (i < n) {
        rowptr[i] = rowptr[i] + boff[i >> 10];
        float deg = (float)(cnt[i] + 1);  // +1 self loop (true degree)
        dinv[i] = 1.0f / sqrtf(deg);
    }
}

// per-graph node counts via binary search over sorted batch (no atomics)
__global__ void k_pcnt_bs(const int* __restrict__ batch, int* __restrict__ pcnt, int n, int ng) {
    int g = blockIdx.x * 256 + threadIdx.x;
    if (g >= ng) return;
    int lo = 0, hi = n;
    while (lo < hi) { int m = (lo + hi) >> 1; if (batch[m] < g) lo = m + 1; else hi = m; }
    int l0 = lo;
    lo = 0; hi = n;
    int v = g + 1;
    while (lo < hi) { int m = (lo + hi) >> 1; if (batch[m] < v) lo = m + 1; else hi = m; }
    pcnt[g] = lo - l0;
}

__global__ void k_fill(const int* __restrict__ src, const int* __restrict__ dst,
                       const int* __restrict__ rank, const int* __restrict__ rowptr,
                       int* __restrict__ colidx, int e) {
    int i = blockIdx.x * 256 + threadIdx.x;
    if (i < e) {
        int d = dst[i];
        colidx[rowptr[d] + rank[i]] = src[i];
    }
}

// ---------- dense GEMM, sliced bf16 in/out ----------
// hs[s][row][16 bf16] = bf16( dinv[row] * sum_k in[row][k] * W[k][s*16 + j] )
// input: BF16IN ? bf16-sliced stride NN (h1) : dense f32 (x)
template <int BF16IN>
__global__ void k_gemm_scale(const void* __restrict__ inv_, const float* __restrict__ W,
                             const float* __restrict__ dinv, unsigned* __restrict__ hs, int n) {
    __shared__ float w[FD * FD];        // 16 KB
    __shared__ float xr[4][4][80];      // padded f32 row staging
    int tid = threadIdx.x;
    {
        const float4* W4 = (const float4*)W;
        float4* w4s = (float4*)w;
        for (int i = tid; i < FD * FD / 4; i += 256) w4s[i] = W4[i];
    }
    int wave = tid >> 6, lane = tid & 63;
    int r = lane >> 4;        // row within wave
    int c = lane & 15;        // 4-feature chunk
    int row = blockIdx.x * 16 + wave * 4 + r;
    bool valid = row < n;
    if (valid) {
        if (BF16IN) {
            uint2 v = ((const uint2*)inv_)[((size_t)(c >> 2) * NN + row) * 4 + (c & 3)];
            xr[wave][r][c * 4 + 0] = bf_lo(v.x);
            xr[wave][r][c * 4 + 1] = bf_hi(v.x);
            xr[wave][r][c * 4 + 2] = bf_lo(v.y);
            xr[wave][r][c * 4 + 3] = bf_hi(v.y);
        } else {
            float4 xv = ((const float4*)inv_)[row * 16 + c];
            *((float4*)&xr[wave][r][c * 4]) = xv;
        }
    }
    __syncthreads();
    if (!valid) return;
    const float4* w4 = (const float4*)w;
    float4 acc = {0.f, 0.f, 0.f, 0.f};
#pragma unroll
    for (int k = 0; k < FD; ++k) {
        float xv = xr[wave][r][k];
        float4 wv = w4[k * 16 + c];
        acc.x = fmaf(xv, wv.x, acc.x);
        acc.y = fmaf(xv, wv.y, acc.y);
        acc.z = fmaf(xv, wv.z, acc.z);
        acc.w = fmaf(xv, wv.w, acc.w);
    }
    float d = dinv[row];
    uint2 o;
    o.x = pack_bf16x2(acc.x * d, acc.y * d);
    o.y = pack_bf16x2(acc.z * d, acc.w * d);
    ((uint2*)hs)[((size_t)(c >> 2) * SR + row) * 4 + (c & 3)] = o;
}

// ---------- sliced aggregation, padded CSR, software-pipelined ----------
// block -> slice = bid&3 (XCD-affine); wave handles 32 nodes serially.
// lane = (slot 0..7, fp 0..7). Degree padded to 16; pads index zero-row NN.
template <int POOL>
__global__ void k_agg4(const unsigned* __restrict__ hs, const int* __restrict__ rowptr,
                       const int* __restrict__ cnt, const int* __restrict__ colidx,
                       const float* __restrict__ dinv, const float* __restrict__ b,
                       const int* __restrict__ batch, void* __restrict__ outp, int n) {
    int bid = blockIdx.x;
    int s = bid & 3;
    int chunk = bid >> 2;
    int tid = threadIdx.x;
    int wave = tid >> 6, lane = tid & 63;
    int slot = lane >> 3, fp = lane & 7;
    const unsigned* S = hs + (size_t)s * SR * 8;   // 3.2 MB slice (8 dwords/row)
    float b0 = b[s * 16 + fp * 2], b1 = b[s * 16 + fp * 2 + 1];
    int node = chunk * CHUNK + wave;
    if (node >= n) return;
    // prologue: first node's state (batches 0 and 1 speculatively; guarded alloc)
    int rs = rowptr[node], ct = cnt[node];
    float dv = dinv[node];
    int bg = POOL ? batch[node] : 0;
    int c0 = colidx[rs + slot];
    int c1 = colidx[rs + 8 + slot];
    int c2 = colidx[rs + 16 + slot];
    int c3 = colidx[rs + 24 + slot];
    for (int t = 0; t < CHUNK / 4; ++t) {
        unsigned w0 = S[(size_t)c0 * 8 + fp];
        unsigned w1 = S[(size_t)c1 * 8 + fp];
        unsigned sv = S[(size_t)node * 8 + fp];   // self row
        // prefetch next node's state
        int node2 = node + 4;
        int ncl = node2 < n ? node2 : n - 1;
        int rs2 = rowptr[ncl], ct2 = cnt[ncl];
        float dv2 = dinv[ncl];
        int bg2 = POOL ? batch[ncl] : 0;
        int nc0 = colidx[rs2 + slot];
        int nc1 = colidx[rs2 + 8 + slot];
        int nc2 = colidx[rs2 + 16 + slot];
        int nc3 = colidx[rs2 + 24 + slot];
        float a0 = 0.f, a1 = 0.f;
        if (ct > 0) {                    // wave-uniform; deg==0 is ~never
            a0 = bf_lo(w0) + bf_lo(w1);
            a1 = bf_hi(w0) + bf_hi(w1);
            if (ct > 16) {               // wave-uniform, ~46%: batch 1 (pre-loaded)
                unsigned w2 = S[(size_t)c2 * 8 + fp];
                unsigned w3 = S[(size_t)c3 * 8 + fp];
                a0 += bf_lo(w2) + bf_lo(w3);
                a1 += bf_hi(w2) + bf_hi(w3);
                if (ct > 32) {           // rare (~0.01%)
                    int e = rs + ((ct + 15) & ~15);
                    for (int i = rs + 32; i < e; i += 16) {
                        int x0 = colidx[i + slot], x1 = colidx[i + 8 + slot];
                        unsigned y0 = S[(size_t)x0 * 8 + fp];
                        unsigned y1 = S[(size_t)x1 * 8 + fp];
                        a0 += bf_lo(y0) + bf_lo(y1);
                        a1 += bf_hi(y0) + bf_hi(y1);
                    }
                }
            }
        }
        // reduce across 8 slots
        a0 += __shfl_xor(a0, 8, 64);  a1 += __shfl_xor(a1, 8, 64);
        a0 += __shfl_xor(a0, 16, 64); a1 += __shfl_xor(a1, 16, 64);
        a0 += __shfl_xor(a0, 32, 64); a1 += __shfl_xor(a1, 32, 64);
        if (lane < 8) {
            float t0 = a0 + bf_lo(sv), t1 = a1 + bf_hi(sv);
            float r0 = fmaxf(fmaf(t0, dv, b0), 0.f);
            float r1 = fmaxf(fmaf(t1, dv, b1), 0.f);
            if (POOL) {
                float* p = &((float*)outp)[((size_t)s * NG + bg) * 16 + fp * 2];
                atomicAdd(p + 0, r0);
                atomicAdd(p + 1, r1);
            } else {
                // bf16-sliced h1: 32 B contiguous per node-slice, XCD-local region
                ((unsigned*)outp)[((size_t)s * NN + node) * 8 + fp] = pack_bf16x2(r0, r1);
            }
        }
        // rotate pipeline state
        node = node2;
        if (node >= n) break;      // uniform within wave
        rs = rs2; ct = ct2; dv = dv2; bg = bg2;
        c0 = nc0; c1 = nc1; c2 = nc2; c3 = nc3;
    }
}

// out[g][o] = (sum_f pool_s[f/16][g][f%16]/cnt[g] * Wfc[f][o]) + bfc[o]; wave/graph
__global__ void k_final(const float* __restrict__ pool, const int* __restrict__ pcnt,
                        const float* __restrict__ Wfc, const float* __restrict__ bfc,
                        float* __restrict__ out, int ng) {
    int tid = threadIdx.x;
    int wave = tid >> 6, lane = tid & 63;
    int g = blockIdx.x * 4 + wave;
    if (g >= ng) return;
    float inv = 1.0f / fmaxf((float)pcnt[g], 1.0f);
    float s = pool[((size_t)(lane >> 4) * NG + g) * 16 + (lane & 15)] * inv;
    float a0 = s * Wfc[lane * 2 + 0];
    float a1 = s * Wfc[lane * 2 + 1];
#pragma unroll
    for (int off = 32; off > 0; off >>= 1) {
        a0 += __shfl_down(a0, off, 64);
        a1 += __shfl_down(a1, off, 64);
    }
    if (lane == 0) {
        out[g * 2 + 0] = a0 + bfc[0];
        out[g * 2 + 1] = a1 + bfc[1];
    }
}

extern "C" void kernel_launch(void* const* d_in, const int* in_sizes, int n_in,
                              void* d_out, int out_size, void* d_ws, size_t ws_size,
                              hipStream_t stream) {
    const float* x    = (const float*)d_in[0];
    const int*   eidx = (const int*)d_in[1];   // [2][NE]: row0 = src, row1 = dst
    const int*   batch= (const int*)d_in[2];
    const float* W1   = (const float*)d_in[3];
    const float* b1   = (const float*)d_in[4];
    const float* W2   = (const float*)d_in[5];
    const float* b2   = (const float*)d_in[6];
    const float* Wfc  = (const float*)d_in[7];
    const float* bfc  = (const float*)d_in[8];
    float* out = (float*)d_out;

    const int* esrc = eidx;
    const int* edst = eidx + NE;

    char* ws = (char*)d_ws;
    size_t off = 0;
    auto alloc = [&](size_t bytes) {
        char* p = ws + off;
        off += (bytes + 255) & ~(size_t)255;
        return p;
    };
    int*      cnt      = (int*)     alloc(NN * 4);
    int*      rowptr   = (int*)     alloc(NN * 4);
    int*      blockSum = (int*)     alloc(128 * 4);
    int*      blockOff = (int*)     alloc(128 * 4);
    float*    dinv     = (float*)   alloc(NN * 4);
    int*      colidx   = (int*)     alloc((size_t)COLCAP * 4);     // padded CSR
    unsigned* hs       = (unsigned*)alloc((size_t)SR * FD * 2);    // bf16 sliced [4][SR][16]
    unsigned* h1       = (unsigned*)alloc((size_t)NN * FD * 2);    // bf16 sliced [4][NN][16]
    float*    pool     = (float*)   alloc((size_t)NSL * NG * 16 * 4);  // sliced [4][NG][16]
    int*      pcnt     = (int*)     alloc(NG * 4);
    // rank aliases h1 (rank last used in k_fill, h1 first written by k_agg4<0>)
    int*      rank     = (int*)h1;
    (void)ws_size;

    const int GE = (NE + 255) / 256;            // 6250
    const int GN = (NN + 255) / 256;            // 391
    const int GR = (NN + 15) / 16;              // gemm: 16 rows/block
    const int GA = ((NN + CHUNK - 1) / CHUNK) * NSL;   // 782*4 = 3128
    const int GI = (COLCAP / 4 + 255) / 256;    // init: 3028

    k_init<<<GI, 256, 0, stream>>>(colidx, cnt, pool, hs);
    k_count_rank<<<GE, 256, 0, stream>>>(edst, cnt, rank, NE);
    k_scan1<<<SCAN_BLOCKS, 256, 0, stream>>>(cnt, rowptr, blockSum, NN);
    k_scan2<<<1, 128, 0, stream>>>(blockSum, blockOff, SCAN_BLOCKS);
    k_scan3<<<GN, 256, 0, stream>>>(rowptr, blockOff, cnt, dinv, NN);
    k_pcnt_bs<<<2, 256, 0, stream>>>(batch, pcnt, NN, NG);
    k_fill<<<GE, 256, 0, stream>>>(esrc, edst, rank, rowptr, colidx, NE);

    // layer 1: hs = bf16_sliced((x @ W1) * dinv); h1 = bf16_sliced(relu(...))
    k_gemm_scale<0><<<GR, 256, 0, stream>>>(x, W1, dinv, hs, NN);
    k_agg4<0><<<GA, 256, 0, stream>>>(hs, rowptr, cnt, colidx, dinv, b1, batch, h1, NN);

    // layer 2: hs = bf16_sliced((h1 @ W2) * dinv); pool += relu(...)
    k_gemm_scale<1><<<GR, 256, 0, stream>>>(h1, W2, dinv, hs, NN);
    k_agg4<1><<<GA, 256, 0, stream>>>(hs, rowptr, cnt, colidx, dinv, b2, batch, pool, NN);

    // readout
    k_final<<<(NG + 3) / 4, 256, 0, stream>>>(pool, pcnt, Wfc, bfc, out, NG);
}

// Round 9
// 375.675 us; speedup vs baseline: 1.1319x; 1.1319x over previous
//
#include <hip/hip_runtime.h>

// TargetModel_78786880077968: 2-layer GCN + mean pool
#define NN 100000      // nodes
#define NE 1600000     // edges
#define NG 512         // graphs
#define FD 64          // feature dim
#define NSL 4          // feature slices (XCD-pinned); 16 bf16 each = 32 B rows
#define CHUNK 128      // nodes per agg block
#define SCAN_CHUNK 1024
#define SCAN_BLOCKS 98  // ceil(NN / SCAN_CHUNK)

// ---- bf16 pack/unpack (RNE; values finite) ----
__device__ inline unsigned pack_bf16x2(float a, float b) {
    unsigned ua = __float_as_uint(a), ub = __float_as_uint(b);
    ua = (ua + 0x7FFFu + ((ua >> 16) & 1u)) >> 16;
    ub = (ub + 0x7FFFu + ((ub >> 16) & 1u)) >> 16;
    return ua | (ub << 16);
}
__device__ inline float bf_lo(unsigned u) { return __uint_as_float(u << 16); }
__device__ inline float bf_hi(unsigned u) { return __uint_as_float(u & 0xFFFF0000u); }

// ---------- CSR build ----------

__global__ void k_count_rank(const int* __restrict__ dst, int* __restrict__ cnt,
                             int* __restrict__ rank, int e) {
    int i = blockIdx.x * 256 + threadIdx.x;
    if (i < e) rank[i] = atomicAdd(&cnt[dst[i]], 1);
}

__global__ void k_scan1(const int* __restrict__ cnt, int* __restrict__ part,
                        int* __restrict__ blockSum, int n) {
    __shared__ int lds[256];
    int tid = threadIdx.x;
    int base = blockIdx.x * SCAN_CHUNK + tid * 4;
    int v0 = (base + 0 < n) ? cnt[base + 0] : 0;
    int v1 = (base + 1 < n) ? cnt[base + 1] : 0;
    int v2 = (base + 2 < n) ? cnt[base + 2] : 0;
    int v3 = (base + 3 < n) ? cnt[base + 3] : 0;
    int s = v0 + v1 + v2 + v3;
    lds[tid] = s;
    __syncthreads();
    for (int off = 1; off < 256; off <<= 1) {
        int t = (tid >= off) ? lds[tid - off] : 0;
        __syncthreads();
        lds[tid] += t;
        __syncthreads();
    }
    int run = lds[tid] - s;
    if (base + 0 < n) part[base + 0] = run; run += v0;
    if (base + 1 < n) part[base + 1] = run; run += v1;
    if (base + 2 < n) part[base + 2] = run; run += v2;
    if (base + 3 < n) part[base + 3] = run;
    if (tid == 255) blockSum[blockIdx.x] = lds[255];
}

__global__ void k_scan2(const int* __restrict__ bs, int* __restrict__ boff, int nb) {
    __shared__ int lds[128];
    int tid = threadIdx.x;
    int v = (tid < nb) ? bs[tid] : 0;
    lds[tid] = v;
    __syncthreads();
    for (int off = 1; off < 128; off <<= 1) {
        int t = (tid >= off) ? lds[tid - off] : 0;
        __syncthreads();
        lds[tid] += t;
        __syncthreads();
    }
    if (tid < nb) boff[tid] = lds[tid] - v;
}

__global__ void k_scan3(int* __restrict__ rowptr, const int* __restrict__ boff,
                        const int* __restrict__ cnt, float* __restrict__ dinv, int n) {
    int i = blockIdx.x * 256 + threadIdx.x;
    if (i < n) {
        rowptr[i] = rowptr[i] + boff[i >> 10];
        float deg = (float)(cnt[i] + 1);  // +1 self loop
        dinv[i] = 1.0f / sqrtf(deg);
    }
}

// per-graph node counts via binary search over sorted batch (no atomics)
__global__ void k_pcnt_bs(const int* __restrict__ batch, int* __restrict__ pcnt, int n, int ng) {
    int g = blockIdx.x * 256 + threadIdx.x;
    if (g >= ng) return;
    int lo = 0, hi = n;
    while (lo < hi) { int m = (lo + hi) >> 1; if (batch[m] < g) lo = m + 1; else hi = m; }
    int l0 = lo;
    lo = 0; hi = n;
    int v = g + 1;
    while (lo < hi) { int m = (lo + hi) >> 1; if (batch[m] < v) lo = m + 1; else hi = m; }
    pcnt[g] = lo - l0;
}

__global__ void k_fill(const int* __restrict__ src, const int* __restrict__ dst,
                       const int* __restrict__ rank, const int* __restrict__ rowptr,
                       int* __restrict__ colidx, int e) {
    int i = blockIdx.x * 256 + threadIdx.x;
    if (i < e) {
        int d = dst[i];
        colidx[rowptr[d] + rank[i]] = src[i];
    }
}

// ---------- dense GEMM, sliced bf16 in/out ----------
// hs[s][row][16 bf16] = bf16( dinv[row] * sum_k in[row][k] * W[k][s*16 + j] )
template <int BF16IN>
__global__ void k_gemm_scale(const void* __restrict__ inv_, const float* __restrict__ W,
                             const float* __restrict__ dinv, unsigned* __restrict__ hs, int n) {
    __shared__ float w[FD * FD];        // 16 KB
    __shared__ float xr[4][4][80];      // padded f32 row staging
    int tid = threadIdx.x;
    {
        const float4* W4 = (const float4*)W;
        float4* w4s = (float4*)w;
        for (int i = tid; i < FD * FD / 4; i += 256) w4s[i] = W4[i];
    }
    int wave = tid >> 6, lane = tid & 63;
    int r = lane >> 4;        // row within wave
    int c = lane & 15;        // 4-feature chunk
    int row = blockIdx.x * 16 + wave * 4 + r;
    bool valid = row < n;
    if (valid) {
        if (BF16IN) {
            uint2 v = ((const uint2*)inv_)[((size_t)(c >> 2) * NN + row) * 4 + (c & 3)];
            xr[wave][r][c * 4 + 0] = bf_lo(v.x);
            xr[wave][r][c * 4 + 1] = bf_hi(v.x);
            xr[wave][r][c * 4 + 2] = bf_lo(v.y);
            xr[wave][r][c * 4 + 3] = bf_hi(v.y);
        } else {
            float4 xv = ((const float4*)inv_)[row * 16 + c];
            *((float4*)&xr[wave][r][c * 4]) = xv;
        }
    }
    __syncthreads();
    if (!valid) return;
    const float4* w4 = (const float4*)w;
    float4 acc = {0.f, 0.f, 0.f, 0.f};
#pragma unroll
    for (int k = 0; k < FD; ++k) {
        float xv = xr[wave][r][k];
        float4 wv = w4[k * 16 + c];
        acc.x = fmaf(xv, wv.x, acc.x);
        acc.y = fmaf(xv, wv.y, acc.y);
        acc.z = fmaf(xv, wv.z, acc.z);
        acc.w = fmaf(xv, wv.w, acc.w);
    }
    float d = dinv[row];
    uint2 o;
    o.x = pack_bf16x2(acc.x * d, acc.y * d);
    o.y = pack_bf16x2(acc.z * d, acc.w * d);
    ((uint2*)hs)[((size_t)(c >> 2) * NN + row) * 4 + (c & 3)] = o;
}

// ---------- sliced aggregation, masked pipeline (round-7 structure) ----------
// block -> slice = bid&3 (XCD-affine); wave handles 32 nodes serially.
// lane = (slot 0..7, fp 0..7). POOL: register-accumulated, flush on graph change.
template <int POOL>
__global__ void k_agg4(const unsigned* __restrict__ hs, const int* __restrict__ rowptr,
                       const int* __restrict__ cnt, const int* __restrict__ colidx,
                       const float* __restrict__ dinv, const float* __restrict__ b,
                       const int* __restrict__ batch, void* __restrict__ outp, int n) {
    int bid = blockIdx.x;
    int s = bid & 3;
    int chunk = bid >> 2;
    int tid = threadIdx.x;
    int wave = tid >> 6, lane = tid & 63;
    int slot = lane >> 3, fp = lane & 7;
    const unsigned* S = hs + (size_t)s * NN * 8;   // 3.2 MB slice (8 dwords/row)
    float b0 = b[s * 16 + fp * 2], b1 = b[s * 16 + fp * 2 + 1];
    int node = chunk * CHUNK + wave;
    if (node >= n) return;
    // prologue: first node's state
    int rs = rowptr[node], ct = cnt[node];
    float dv = dinv[node];
    int bg = POOL ? batch[node] : 0;
    int c0 = colidx[rs + slot];
    int c1 = colidx[rs + 8 + slot];
    int curg = bg;
    float p0 = 0.f, p1 = 0.f;          // pool accumulators (valid on all lanes)
    for (int t = 0; t < CHUNK / 4; ++t) {
        bool ok0 = slot < ct, ok1 = slot + 8 < ct;
        int i0 = ok0 ? c0 : node;
        int i1 = ok1 ? c1 : node;
        unsigned w0 = S[(size_t)i0 * 8 + fp];
        unsigned w1 = S[(size_t)i1 * 8 + fp];
        unsigned sv = S[(size_t)node * 8 + fp];   // self row
        // prefetch next node's state (independent of current gathers)
        int node2 = node + 4;
        int ncl = node2 < n ? node2 : n - 1;
        int rs2 = rowptr[ncl], ct2 = cnt[ncl];
        float dv2 = dinv[ncl];
        int bg2 = POOL ? batch[ncl] : 0;
        int nc0 = colidx[rs2 + slot];
        int nc1 = colidx[rs2 + 8 + slot];
        // accumulate (masked)
        w0 = ok0 ? w0 : 0u;
        w1 = ok1 ? w1 : 0u;
        float a0 = bf_lo(w0) + bf_lo(w1);
        float a1 = bf_hi(w0) + bf_hi(w1);
        // tail for degree > 16
        int e = rs + ct;
        for (int i = rs + 16; i < e; i += 8) {
            int cc = colidx[i + slot];
            bool ok = (i + slot) < e;
            int ii = ok ? cc : node;
            unsigned ww = S[(size_t)ii * 8 + fp];
            ww = ok ? ww : 0u;
            a0 += bf_lo(ww);
            a1 += bf_hi(ww);
        }
        // full reduce across 8 slots -> every lane holds the fp-sum
        a0 += __shfl_xor(a0, 8, 64);  a1 += __shfl_xor(a1, 8, 64);
        a0 += __shfl_xor(a0, 16, 64); a1 += __shfl_xor(a1, 16, 64);
        a0 += __shfl_xor(a0, 32, 64); a1 += __shfl_xor(a1, 32, 64);
        float t0 = a0 + bf_lo(sv), t1 = a1 + bf_hi(sv);
        float r0 = fmaxf(fmaf(t0, dv, b0), 0.f);
        float r1 = fmaxf(fmaf(t1, dv, b1), 0.f);
        if (POOL) {
            if (bg != curg) {          // wave-uniform (batch sorted, node uniform)
                if (lane < 8) {
                    float* p = &((float*)outp)[((size_t)s * NG + curg) * 16 + fp * 2];
                    atomicAdd(p + 0, p0);
                    atomicAdd(p + 1, p1);
                }
                curg = bg; p0 = 0.f; p1 = 0.f;
            }
            p0 += r0; p1 += r1;
        } else if (lane < 8) {
            // bf16-sliced h1: 32 B contiguous per node-slice, XCD-local region
            ((unsigned*)outp)[((size_t)s * NN + node) * 8 + fp] = pack_bf16x2(r0, r1);
        }
        // rotate pipeline state
        node = node2;
        if (node >= n) break;          // uniform within wave
        rs = rs2; ct = ct2; dv = dv2; bg = bg2; c0 = nc0; c1 = nc1;
    }
    if (POOL && lane < 8) {            // final flush
        float* p = &((float*)outp)[((size_t)s * NG + curg) * 16 + fp * 2];
        atomicAdd(p + 0, p0);
        atomicAdd(p + 1, p1);
    }
}

// out[g][o] = (sum_f pool_s[f/16][g][f%16]/cnt[g] * Wfc[f][o]) + bfc[o]; wave/graph
__global__ void k_final(const float* __restrict__ pool, const int* __restrict__ pcnt,
                        const float* __restrict__ Wfc, const float* __restrict__ bfc,
                        float* __restrict__ out, int ng) {
    int tid = threadIdx.x;
    int wave = tid >> 6, lane = tid & 63;
    int g = blockIdx.x * 4 + wave;
    if (g >= ng) return;
    float inv = 1.0f / fmaxf((float)pcnt[g], 1.0f);
    float s = pool[((size_t)(lane >> 4) * NG + g) * 16 + (lane & 15)] * inv;
    float a0 = s * Wfc[lane * 2 + 0];
    float a1 = s * Wfc[lane * 2 + 1];
#pragma unroll
    for (int off = 32; off > 0; off >>= 1) {
        a0 += __shfl_down(a0, off, 64);
        a1 += __shfl_down(a1, off, 64);
    }
    if (lane == 0) {
        out[g * 2 + 0] = a0 + bfc[0];
        out[g * 2 + 1] = a1 + bfc[1];
    }
}

extern "C" void kernel_launch(void* const* d_in, const int* in_sizes, int n_in,
                              void* d_out, int out_size, void* d_ws, size_t ws_size,
                              hipStream_t stream) {
    const float* x    = (const float*)d_in[0];
    const int*   eidx = (const int*)d_in[1];   // [2][NE]: row0 = src, row1 = dst
    const int*   batch= (const int*)d_in[2];
    const float* W1   = (const float*)d_in[3];
    const float* b1   = (const float*)d_in[4];
    const float* W2   = (const float*)d_in[5];
    const float* b2   = (const float*)d_in[6];
    const float* Wfc  = (const float*)d_in[7];
    const float* bfc  = (const float*)d_in[8];
    float* out = (float*)d_out;

    const int* esrc = eidx;
    const int* edst = eidx + NE;

    char* ws = (char*)d_ws;
    size_t off = 0;
    auto alloc = [&](size_t bytes) {
        char* p = ws + off;
        off += (bytes + 255) & ~(size_t)255;
        return p;
    };
    int*      cnt      = (int*)     alloc(NN * 4);
    int*      rowptr   = (int*)     alloc(NN * 4);
    int*      blockSum = (int*)     alloc(128 * 4);
    int*      blockOff = (int*)     alloc(128 * 4);
    float*    dinv     = (float*)   alloc(NN * 4);
    int*      colidx   = (int*)     alloc((size_t)(NE + 64) * 4);  // +pad for slot overreach
    unsigned* hs       = (unsigned*)alloc((size_t)NN * FD * 2);    // bf16 sliced [4][NN][16]
    unsigned* h1       = (unsigned*)alloc((size_t)NN * FD * 2);    // bf16 sliced [4][NN][16]
    float*    pool     = (float*)   alloc((size_t)NSL * NG * 16 * 4);  // sliced [4][NG][16]
    int*      pcnt     = (int*)     alloc(NG * 4);
    // rank aliases h1 (rank last used in k_fill, h1 first written by k_agg4<0>)
    int*      rank     = (int*)h1;
    (void)ws_size;

    hipMemsetAsync(cnt,  0, NN * 4, stream);
    hipMemsetAsync(pool, 0, (size_t)NSL * NG * 16 * 4, stream);

    const int GE = (NE + 255) / 256;   // 6250
    const int GN = (NN + 255) / 256;   // 391
    const int GR = (NN + 15) / 16;     // gemm: 16 rows/block
    const int GA = ((NN + CHUNK - 1) / CHUNK) * NSL;   // 782*4 = 3128

    k_count_rank<<<GE, 256, 0, stream>>>(edst, cnt, rank, NE);
    k_scan1<<<SCAN_BLOCKS, 256, 0, stream>>>(cnt, rowptr, blockSum, NN);
    k_scan2<<<1, 128, 0, stream>>>(blockSum, blockOff, SCAN_BLOCKS);
    k_scan3<<<GN, 256, 0, stream>>>(rowptr, blockOff, cnt, dinv, NN);
    k_pcnt_bs<<<2, 256, 0, stream>>>(batch, pcnt, NN, NG);
    k_fill<<<GE, 256, 0, stream>>>(esrc, edst, rank, rowptr, colidx, NE);

    // layer 1: hs = bf16_sliced((x @ W1) * dinv); h1 = bf16_sliced(relu(...))
    k_gemm_scale<0><<<GR, 256, 0, stream>>>(x, W1, dinv, hs, NN);
    k_agg4<0><<<GA, 256, 0, stream>>>(hs, rowptr, cnt, colidx, dinv, b1, batch, h1, NN);

    // layer 2: hs = bf16_sliced((h1 @ W2) * dinv); pool += relu(...)
    k_gemm_scale<1><<<GR, 256, 0, stream>>>(h1, W2, dinv, hs, NN);
    k_agg4<1><<<GA, 256, 0, stream>>>(hs, rowptr, cnt, colidx, dinv, b2, batch, pool, NN);

    // readout
    k_final<<<(NG + 3) / 4, 256, 0, stream>>>(pool, pcnt, Wfc, bfc, out, NG);
}

// Round 10
// 373.916 us; speedup vs baseline: 1.1372x; 1.0047x over previous
//
#include <hip/hip_runtime.h>
#include <hip/hip_fp16.h>

// TargetModel_78786880077968: 2-layer GCN + mean pool
#define NN 100000      // nodes
#define NE 1600000     // edges
#define NG 512         // graphs
#define FD 64          // feature dim
#define NSL 4          // feature slices (XCD-pinned); 16 fp16 each = 32 B rows
#define CHUNK 128      // nodes per agg block
#define SCAN_CHUNK 1024
#define SCAN_BLOCKS 98  // ceil(NN / SCAN_CHUNK)

// ---- fp16 pack/unpack ----
union U32H2 { unsigned u; __half2 h; };
__device__ inline __half2 h2(unsigned v) { U32H2 c; c.u = v; return c.h; }
__device__ inline unsigned uh(__half2 v) { U32H2 c; c.h = v; return c.u; }
__device__ inline unsigned pack_f16x2(float a, float b) {
    return uh(__floats2half2_rn(a, b));
}

// ---------- CSR build ----------

__global__ void k_count_rank(const int* __restrict__ dst, int* __restrict__ cnt,
                             int* __restrict__ rank, int e) {
    int i = blockIdx.x * 256 + threadIdx.x;
    if (i < e) rank[i] = atomicAdd(&cnt[dst[i]], 1);
}

__global__ void k_scan1(const int* __restrict__ cnt, int* __restrict__ part,
                        int* __restrict__ blockSum, int n) {
    __shared__ int lds[256];
    int tid = threadIdx.x;
    int base = blockIdx.x * SCAN_CHUNK + tid * 4;
    int v0 = (base + 0 < n) ? cnt[base + 0] : 0;
    int v1 = (base + 1 < n) ? cnt[base + 1] : 0;
    int v2 = (base + 2 < n) ? cnt[base + 2] : 0;
    int v3 = (base + 3 < n) ? cnt[base + 3] : 0;
    int s = v0 + v1 + v2 + v3;
    lds[tid] = s;
    __syncthreads();
    for (int off = 1; off < 256; off <<= 1) {
        int t = (tid >= off) ? lds[tid - off] : 0;
        __syncthreads();
        lds[tid] += t;
        __syncthreads();
    }
    int run = lds[tid] - s;
    if (base + 0 < n) part[base + 0] = run; run += v0;
    if (base + 1 < n) part[base + 1] = run; run += v1;
    if (base + 2 < n) part[base + 2] = run; run += v2;
    if (base + 3 < n) part[base + 3] = run;
    if (tid == 255) blockSum[blockIdx.x] = lds[255];
}

__global__ void k_scan2(const int* __restrict__ bs, int* __restrict__ boff, int nb) {
    __shared__ int lds[128];
    int tid = threadIdx.x;
    int v = (tid < nb) ? bs[tid] : 0;
    lds[tid] = v;
    __syncthreads();
    for (int off = 1; off < 128; off <<= 1) {
        int t = (tid >= off) ? lds[tid - off] : 0;
        __syncthreads();
        lds[tid] += t;
        __syncthreads();
    }
    if (tid < nb) boff[tid] = lds[tid] - v;
}

__global__ void k_scan3(int* __restrict__ rowptr, const int* __restrict__ boff,
                        const int* __restrict__ cnt, float* __restrict__ dinv, int n) {
    int i = blockIdx.x * 256 + threadIdx.x;
    if (i < n) {
        rowptr[i] = rowptr[i] + boff[i >> 10];
        float deg = (float)(cnt[i] + 1);  // +1 self loop
        dinv[i] = 1.0f / sqrtf(deg);
    }
}

// per-graph node counts via binary search over sorted batch (no atomics)
__global__ void k_pcnt_bs(const int* __restrict__ batch, int* __restrict__ pcnt, int n, int ng) {
    int g = blockIdx.x * 256 + threadIdx.x;
    if (g >= ng) return;
    int lo = 0, hi = n;
    while (lo < hi) { int m = (lo + hi) >> 1; if (batch[m] < g) lo = m + 1; else hi = m; }
    int l0 = lo;
    lo = 0; hi = n;
    int v = g + 1;
    while (lo < hi) { int m = (lo + hi) >> 1; if (batch[m] < v) lo = m + 1; else hi = m; }
    pcnt[g] = lo - l0;
}

__global__ void k_fill(const int* __restrict__ src, const int* __restrict__ dst,
                       const int* __restrict__ rank, const int* __restrict__ rowptr,
                       int* __restrict__ colidx, int e) {
    int i = blockIdx.x * 256 + threadIdx.x;
    if (i < e) {
        int d = dst[i];
        colidx[rowptr[d] + rank[i]] = src[i];
    }
}

// ---------- dense GEMM, sliced fp16 in/out ----------
// hs[s][row][16 fp16] = f16( dinv[row] * sum_k in[row][k] * W[k][s*16 + j] )
template <int F16IN>
__global__ void k_gemm_scale(const void* __restrict__ inv_, const float* __restrict__ W,
                             const float* __restrict__ dinv, unsigned* __restrict__ hs, int n) {
    __shared__ float w[FD * FD];        // 16 KB
    __shared__ float xr[4][4][80];      // padded f32 row staging
    int tid = threadIdx.x;
    {
        const float4* W4 = (const float4*)W;
        float4* w4s = (float4*)w;
        for (int i = tid; i < FD * FD / 4; i += 256) w4s[i] = W4[i];
    }
    int wave = tid >> 6, lane = tid & 63;
    int r = lane >> 4;        // row within wave
    int c = lane & 15;        // 4-feature chunk
    int row = blockIdx.x * 16 + wave * 4 + r;
    bool valid = row < n;
    if (valid) {
        if (F16IN) {
            uint2 v = ((const uint2*)inv_)[((size_t)(c >> 2) * NN + row) * 4 + (c & 3)];
            float2 f0 = __half22float2(h2(v.x));
            float2 f1 = __half22float2(h2(v.y));
            xr[wave][r][c * 4 + 0] = f0.x;
            xr[wave][r][c * 4 + 1] = f0.y;
            xr[wave][r][c * 4 + 2] = f1.x;
            xr[wave][r][c * 4 + 3] = f1.y;
        } else {
            float4 xv = ((const float4*)inv_)[row * 16 + c];
            *((float4*)&xr[wave][r][c * 4]) = xv;
        }
    }
    __syncthreads();
    if (!valid) return;
    const float4* w4 = (const float4*)w;
    float4 acc = {0.f, 0.f, 0.f, 0.f};
#pragma unroll
    for (int k = 0; k < FD; ++k) {
        float xv = xr[wave][r][k];
        float4 wv = w4[k * 16 + c];
        acc.x = fmaf(xv, wv.x, acc.x);
        acc.y = fmaf(xv, wv.y, acc.y);
        acc.z = fmaf(xv, wv.z, acc.z);
        acc.w = fmaf(xv, wv.w, acc.w);
    }
    float d = dinv[row];
    uint2 o;
    o.x = pack_f16x2(acc.x * d, acc.y * d);
    o.y = pack_f16x2(acc.z * d, acc.w * d);
    ((uint2*)hs)[((size_t)(c >> 2) * NN + row) * 4 + (c & 3)] = o;
}

// ---------- sliced aggregation, packed-fp16 accumulate ----------
// block -> slice = bid&3 (XCD-affine); wave handles 32 nodes serially.
// lane = (slot 0..7, fp 0..7). POOL: register-accumulated, flush on graph change.
template <int POOL>
__global__ void k_agg4(const unsigned* __restrict__ hs, const int* __restrict__ rowptr,
                       const int* __restrict__ cnt, const int* __restrict__ colidx,
                       const float* __restrict__ dinv, const float* __restrict__ b,
                       const int* __restrict__ batch, void* __restrict__ outp, int n) {
    int bid = blockIdx.x;
    int s = bid & 3;
    int chunk = bid >> 2;
    int tid = threadIdx.x;
    int wave = tid >> 6, lane = tid & 63;
    int slot = lane >> 3, fp = lane & 7;
    const unsigned* S = hs + (size_t)s * NN * 8;   // 3.2 MB slice (8 dwords/row)
    float b0 = b[s * 16 + fp * 2], b1 = b[s * 16 + fp * 2 + 1];
    int node = chunk * CHUNK + wave;
    if (node >= n) return;
    // prologue: first node's state
    int rs = rowptr[node], ct = cnt[node];
    float dv = dinv[node];
    int bg = POOL ? batch[node] : 0;
    int c0 = colidx[rs + slot];
    int c1 = colidx[rs + 8 + slot];
    int curg = bg;
    float p0 = 0.f, p1 = 0.f;          // pool accumulators
    for (int t = 0; t < CHUNK / 4; ++t) {
        bool ok0 = slot < ct, ok1 = slot + 8 < ct;
        int i0 = ok0 ? c0 : node;
        int i1 = ok1 ? c1 : node;
        unsigned w0 = S[(size_t)i0 * 8 + fp];
        unsigned w1 = S[(size_t)i1 * 8 + fp];
        unsigned sv = S[(size_t)node * 8 + fp];   // self row
        // prefetch next node's state (independent of current gathers)
        int node2 = node + 4;
        int ncl = node2 < n ? node2 : n - 1;
        int rs2 = rowptr[ncl], ct2 = cnt[ncl];
        float dv2 = dinv[ncl];
        int bg2 = POOL ? batch[ncl] : 0;
        int nc0 = colidx[rs2 + slot];
        int nc1 = colidx[rs2 + 8 + slot];
        // packed fp16 accumulate (masked)
        w0 = ok0 ? w0 : 0u;
        w1 = ok1 ? w1 : 0u;
        __half2 acc = __hadd2(h2(w0), h2(w1));
        // tail for degree > 16
        int e = rs + ct;
        for (int i = rs + 16; i < e; i += 8) {
            int cc = colidx[i + slot];
            bool ok = (i + slot) < e;
            int ii = ok ? cc : node;
            unsigned ww = S[(size_t)ii * 8 + fp];
            ww = ok ? ww : 0u;
            acc = __hadd2(acc, h2(ww));
        }
        // reduce across 8 slots (packed)
        acc = __hadd2(acc, h2(__shfl_xor(uh(acc), 8, 64)));
        acc = __hadd2(acc, h2(__shfl_xor(uh(acc), 16, 64)));
        acc = __hadd2(acc, h2(__shfl_xor(uh(acc), 32, 64)));
        float2 av = __half22float2(acc);
        float2 sf = __half22float2(h2(sv));
        float r0 = fmaxf(fmaf(av.x + sf.x, dv, b0), 0.f);
        float r1 = fmaxf(fmaf(av.y + sf.y, dv, b1), 0.f);
        if (POOL) {
            if (bg != curg) {          // wave-uniform (batch sorted, node uniform)
                if (lane < 8) {
                    float* p = &((float*)outp)[((size_t)s * NG + curg) * 16 + fp * 2];
                    atomicAdd(p + 0, p0);
                    atomicAdd(p + 1, p1);
                }
                curg = bg; p0 = 0.f; p1 = 0.f;
            }
            p0 += r0; p1 += r1;
        } else if (lane < 8) {
            // fp16-sliced h1: 32 B contiguous per node-slice, XCD-local region
            ((unsigned*)outp)[((size_t)s * NN + node) * 8 + fp] = pack_f16x2(r0, r1);
        }
        // rotate pipeline state
        node = node2;
        if (node >= n) break;          // uniform within wave
        rs = rs2; ct = ct2; dv = dv2; bg = bg2; c0 = nc0; c1 = nc1;
    }
    if (POOL && lane < 8) {            // final flush
        float* p = &((float*)outp)[((size_t)s * NG + curg) * 16 + fp * 2];
        atomicAdd(p + 0, p0);
        atomicAdd(p + 1, p1);
    }
}

// out[g][o] = (sum_f pool_s[f/16][g][f%16]/cnt[g] * Wfc[f][o]) + bfc[o]; wave/graph
__global__ void k_final(const float* __restrict__ pool, const int* __restrict__ pcnt,
                        const float* __restrict__ Wfc, const float* __restrict__ bfc,
                        float* __restrict__ out, int ng) {
    int tid = threadIdx.x;
    int wave = tid >> 6, lane = tid & 63;
    int g = blockIdx.x * 4 + wave;
    if (g >= ng) return;
    float inv = 1.0f / fmaxf((float)pcnt[g], 1.0f);
    float s = pool[((size_t)(lane >> 4) * NG + g) * 16 + (lane & 15)] * inv;
    float a0 = s * Wfc[lane * 2 + 0];
    float a1 = s * Wfc[lane * 2 + 1];
#pragma unroll
    for (int off = 32; off > 0; off >>= 1) {
        a0 += __shfl_down(a0, off, 64);
        a1 += __shfl_down(a1, off, 64);
    }
    if (lane == 0) {
        out[g * 2 + 0] = a0 + bfc[0];
        out[g * 2 + 1] = a1 + bfc[1];
    }
}

extern "C" void kernel_launch(void* const* d_in, const int* in_sizes, int n_in,
                              void* d_out, int out_size, void* d_ws, size_t ws_size,
                              hipStream_t stream) {
    const float* x    = (const float*)d_in[0];
    const int*   eidx = (const int*)d_in[1];   // [2][NE]: row0 = src, row1 = dst
    const int*   batch= (const int*)d_in[2];
    const float* W1   = (const float*)d_in[3];
    const float* b1   = (const float*)d_in[4];
    const float* W2   = (const float*)d_in[5];
    const float* b2   = (const float*)d_in[6];
    const float* Wfc  = (const float*)d_in[7];
    const float* bfc  = (const float*)d_in[8];
    float* out = (float*)d_out;

    const int* esrc = eidx;
    const int* edst = eidx + NE;

    char* ws = (char*)d_ws;
    size_t off = 0;
    auto alloc = [&](size_t bytes) {
        char* p = ws + off;
        off += (bytes + 255) & ~(size_t)255;
        return p;
    };
    int*      cnt      = (int*)     alloc(NN * 4);
    int*      rowptr   = (int*)     alloc(NN * 4);
    int*      blockSum = (int*)     alloc(128 * 4);
    int*      blockOff = (int*)     alloc(128 * 4);
    float*    dinv     = (float*)   alloc(NN * 4);
    int*      colidx   = (int*)     alloc((size_t)(NE + 64) * 4);  // +pad for slot overreach
    unsigned* hs       = (unsigned*)alloc((size_t)NN * FD * 2);    // fp16 sliced [4][NN][16]
    unsigned* h1       = (unsigned*)alloc((size_t)NN * FD * 2);    // fp16 sliced [4][NN][16]
    float*    pool     = (float*)   alloc((size_t)NSL * NG * 16 * 4);  // sliced [4][NG][16]
    int*      pcnt     = (int*)     alloc(NG * 4);
    // rank aliases h1 (rank last used in k_fill, h1 first written by k_agg4<0>)
    int*      rank     = (int*)h1;
    (void)ws_size;

    hipMemsetAsync(cnt,  0, NN * 4, stream);
    hipMemsetAsync(pool, 0, (size_t)NSL * NG * 16 * 4, stream);

    const int GE = (NE + 255) / 256;   // 6250
    const int GN = (NN + 255) / 256;   // 391
    const int GR = (NN + 15) / 16;     // gemm: 16 rows/block
    const int GA = ((NN + CHUNK - 1) / CHUNK) * NSL;   // 782*4 = 3128

    k_count_rank<<<GE, 256, 0, stream>>>(edst, cnt, rank, NE);
    k_scan1<<<SCAN_BLOCKS, 256, 0, stream>>>(cnt, rowptr, blockSum, NN);
    k_scan2<<<1, 128, 0, stream>>>(blockSum, blockOff, SCAN_BLOCKS);
    k_scan3<<<GN, 256, 0, stream>>>(rowptr, blockOff, cnt, dinv, NN);
    k_pcnt_bs<<<2, 256, 0, stream>>>(batch, pcnt, NN, NG);
    k_fill<<<GE, 256, 0, stream>>>(esrc, edst, rank, rowptr, colidx, NE);

    // layer 1: hs = f16_sliced((x @ W1) * dinv); h1 = f16_sliced(relu(...))
    k_gemm_scale<0><<<GR, 256, 0, stream>>>(x, W1, dinv, hs, NN);
    k_agg4<0><<<GA, 256, 0, stream>>>(hs, rowptr, cnt, colidx, dinv, b1, batch, h1, NN);

    // layer 2: hs = f16_sliced((h1 @ W2) * dinv); pool += relu(...)
    k_gemm_scale<1><<<GR, 256, 0, stream>>>(h1, W2, dinv, hs, NN);
    k_agg4<1><<<GA, 256, 0, stream>>>(hs, rowptr, cnt, colidx, dinv, b2, batch, pool, NN);

    // readout
    k_final<<<(NG + 3) / 4, 256, 0, stream>>>(pool, pcnt, Wfc, bfc, out, NG);
}

// Round 11
// 362.953 us; speedup vs baseline: 1.1716x; 1.0302x over previous
//
#include <hip/hip_runtime.h>
#include <hip/hip_fp16.h>

// TargetModel_78786880077968: 2-layer GCN + mean pool
#define NN 100000      // nodes
#define NE 1600000     // edges
#define NG 512         // graphs
#define FD 64          // feature dim
#define NSL 4          // feature slices (XCD-pinned); 16 fp16 each = 32 B rows
#define CHUNK 128      // nodes per agg block
#define SCAN_CHUNK 1024
#define SCAN_BLOCKS 98  // ceil(NN / SCAN_CHUNK)

// ---- fp16 pack/unpack ----
union U32H2 { unsigned u; __half2 h; };
__device__ inline __half2 h2(unsigned v) { U32H2 c; c.u = v; return c.h; }
__device__ inline unsigned uh(__half2 v) { U32H2 c; c.h = v; return c.u; }
__device__ inline unsigned pack_f16x2(float a, float b) {
    return uh(__floats2half2_rn(a, b));
}

// ---------- CSR build ----------

__global__ void k_count_rank(const int* __restrict__ dst, int* __restrict__ cnt,
                             int* __restrict__ rank, int e) {
    int i = blockIdx.x * 256 + threadIdx.x;
    if (i < e) rank[i] = atomicAdd(&cnt[dst[i]], 1);
}

__global__ void k_scan1(const int* __restrict__ cnt, int* __restrict__ part,
                        int* __restrict__ blockSum, int n) {
    __shared__ int lds[256];
    int tid = threadIdx.x;
    int base = blockIdx.x * SCAN_CHUNK + tid * 4;
    int v0 = (base + 0 < n) ? cnt[base + 0] : 0;
    int v1 = (base + 1 < n) ? cnt[base + 1] : 0;
    int v2 = (base + 2 < n) ? cnt[base + 2] : 0;
    int v3 = (base + 3 < n) ? cnt[base + 3] : 0;
    int s = v0 + v1 + v2 + v3;
    lds[tid] = s;
    __syncthreads();
    for (int off = 1; off < 256; off <<= 1) {
        int t = (tid >= off) ? lds[tid - off] : 0;
        __syncthreads();
        lds[tid] += t;
        __syncthreads();
    }
    int run = lds[tid] - s;
    if (base + 0 < n) part[base + 0] = run; run += v0;
    if (base + 1 < n) part[base + 1] = run; run += v1;
    if (base + 2 < n) part[base + 2] = run; run += v2;
    if (base + 3 < n) part[base + 3] = run;
    if (tid == 255) blockSum[blockIdx.x] = lds[255];
}

__global__ void k_scan2(const int* __restrict__ bs, int* __restrict__ boff, int nb) {
    __shared__ int lds[128];
    int tid = threadIdx.x;
    int v = (tid < nb) ? bs[tid] : 0;
    lds[tid] = v;
    __syncthreads();
    for (int off = 1; off < 128; off <<= 1) {
        int t = (tid >= off) ? lds[tid - off] : 0;
        __syncthreads();
        lds[tid] += t;
        __syncthreads();
    }
    if (tid < nb) boff[tid] = lds[tid] - v;
}

__global__ void k_scan3(int* __restrict__ rowptr, const int* __restrict__ boff,
                        const int* __restrict__ cnt, float* __restrict__ dinv, int n) {
    int i = blockIdx.x * 256 + threadIdx.x;
    if (i < n) {
        rowptr[i] = rowptr[i] + boff[i >> 10];
        float deg = (float)(cnt[i] + 1);  // +1 self loop
        dinv[i] = 1.0f / sqrtf(deg);
    }
}

// per-graph node counts via binary search over sorted batch (no atomics)
__global__ void k_pcnt_bs(const int* __restrict__ batch, int* __restrict__ pcnt, int n, int ng) {
    int g = blockIdx.x * 256 + threadIdx.x;
    if (g >= ng) return;
    int lo = 0, hi = n;
    while (lo < hi) { int m = (lo + hi) >> 1; if (batch[m] < g) lo = m + 1; else hi = m; }
    int l0 = lo;
    lo = 0; hi = n;
    int v = g + 1;
    while (lo < hi) { int m = (lo + hi) >> 1; if (batch[m] < v) lo = m + 1; else hi = m; }
    pcnt[g] = lo - l0;
}

__global__ void k_fill(const int* __restrict__ src, const int* __restrict__ dst,
                       const int* __restrict__ rank, const int* __restrict__ rowptr,
                       int* __restrict__ colidx, int e) {
    int i = blockIdx.x * 256 + threadIdx.x;
    if (i < e) {
        int d = dst[i];
        colidx[rowptr[d] + rank[i]] = src[i];
    }
}

// ---------- dense GEMM, sliced fp16 in/out ----------
// hs[s][row][16 fp16] = f16( dinv[row] * sum_k in[row][k] * W[k][s*16 + j] )
template <int F16IN>
__global__ void k_gemm_scale(const void* __restrict__ inv_, const float* __restrict__ W,
                             const float* __restrict__ dinv, unsigned* __restrict__ hs, int n) {
    __shared__ float w[FD * FD];        // 16 KB
    __shared__ float xr[4][4][80];      // padded f32 row staging
    int tid = threadIdx.x;
    {
        const float4* W4 = (const float4*)W;
        float4* w4s = (float4*)w;
        for (int i = tid; i < FD * FD / 4; i += 256) w4s[i] = W4[i];
    }
    int wave = tid >> 6, lane = tid & 63;
    int r = lane >> 4;        // row within wave
    int c = lane & 15;        // 4-feature chunk
    int row = blockIdx.x * 16 + wave * 4 + r;
    bool valid = row < n;
    if (valid) {
        if (F16IN) {
            uint2 v = ((const uint2*)inv_)[((size_t)(c >> 2) * NN + row) * 4 + (c & 3)];
            float2 f0 = __half22float2(h2(v.x));
            float2 f1 = __half22float2(h2(v.y));
            xr[wave][r][c * 4 + 0] = f0.x;
            xr[wave][r][c * 4 + 1] = f0.y;
            xr[wave][r][c * 4 + 2] = f1.x;
            xr[wave][r][c * 4 + 3] = f1.y;
        } else {
            float4 xv = ((const float4*)inv_)[row * 16 + c];
            *((float4*)&xr[wave][r][c * 4]) = xv;
        }
    }
    __syncthreads();
    if (!valid) return;
    const float4* w4 = (const float4*)w;
    float4 acc = {0.f, 0.f, 0.f, 0.f};
#pragma unroll
    for (int k = 0; k < FD; ++k) {
        float xv = xr[wave][r][k];
        float4 wv = w4[k * 16 + c];
        acc.x = fmaf(xv, wv.x, acc.x);
        acc.y = fmaf(xv, wv.y, acc.y);
        acc.z = fmaf(xv, wv.z, acc.z);
        acc.w = fmaf(xv, wv.w, acc.w);
    }
    float d = dinv[row];
    uint2 o;
    o.x = pack_f16x2(acc.x * d, acc.y * d);
    o.y = pack_f16x2(acc.z * d, acc.w * d);
    ((uint2*)hs)[((size_t)(c >> 2) * NN + row) * 4 + (c & 3)] = o;
}

// ---- gather issue helper (clamp indices BEFORE load; mask result) ----
struct G5 { unsigned w0, w1, w2, w3, sv; };
__device__ inline G5 issue_gather(const unsigned* __restrict__ S,
                                  int c0, int c1, int c2, int c3,
                                  int ct, int nc, int slot, int fp) {
    G5 g;
    bool o0 = slot < ct, o1 = slot + 8 < ct;
    int i0 = o0 ? c0 : nc;
    int i1 = o1 ? c1 : nc;
    unsigned t0 = S[(size_t)i0 * 8 + fp];
    unsigned t1 = S[(size_t)i1 * 8 + fp];
    g.sv = S[(size_t)nc * 8 + fp];
    g.w0 = o0 ? t0 : 0u;
    g.w1 = o1 ? t1 : 0u;
    g.w2 = 0u; g.w3 = 0u;
    if (ct > 16) {                      // wave-uniform branch
        bool o2 = slot + 16 < ct, o3 = slot + 24 < ct;
        int i2 = o2 ? c2 : nc;
        int i3 = o3 ? c3 : nc;
        unsigned t2 = S[(size_t)i2 * 8 + fp];
        unsigned t3 = S[(size_t)i3 * 8 + fp];
        g.w2 = o2 ? t2 : 0u;
        g.w3 = o3 ? t3 : 0u;
    }
    return g;
}

// ---------- sliced aggregation, 3-stage decoupled pipeline ----------
// block -> slice = bid&3 (XCD-affine); wave handles 32 nodes (stride 4).
// iteration t: consume gathers(node t) | issue gathers(t+1) | colidx(t+2) | meta(t+3)
template <int POOL>
__global__ void k_agg4(const unsigned* __restrict__ hs, const int* __restrict__ rowptr,
                       const int* __restrict__ cnt, const int* __restrict__ colidx,
                       const float* __restrict__ dinv, const float* __restrict__ b,
                       const int* __restrict__ batch, void* __restrict__ outp, int n) {
    int bid = blockIdx.x;
    int s = bid & 3;
    int chunk = bid >> 2;
    int tid = threadIdx.x;
    int wave = tid >> 6, lane = tid & 63;
    int slot = lane >> 3, fp = lane & 7;
    const unsigned* S = hs + (size_t)s * NN * 8;   // 3.2 MB slice (8 dwords/row)
    float b0 = b[s * 16 + fp * 2], b1 = b[s * 16 + fp * 2 + 1];

    int base = chunk * CHUNK + wave;               // nodes: base + 4t, t in [0,32)
    auto cl = [n](int i) { return i < n ? i : n - 1; };

    // ---- prologue: fill 3 pipeline stages ----
    int nA = cl(base);
    int rsA = rowptr[nA], ctA = cnt[nA];
    float dvA = dinv[nA];
    int bgA = POOL ? batch[nA] : 0;
    int nB = cl(base + 4);
    int rsB = rowptr[nB], ctB = cnt[nB];
    float dvB = dinv[nB];
    int bgB = POOL ? batch[nB] : 0;
    int nC = cl(base + 8);
    int rsC = rowptr[nC], ctC = cnt[nC];
    float dvC = dinv[nC];
    int bgC = POOL ? batch[nC] : 0;

    // colidx for stage A (node base) and stage B (base+4)
    int cA0 = colidx[rsA + slot];
    int cA1 = colidx[rsA + 8 + slot];
    int cA2 = 0, cA3 = 0;
    if (ctA > 16) { cA2 = colidx[rsA + 16 + slot]; cA3 = colidx[rsA + 24 + slot]; }
    int cB0 = colidx[rsB + slot];
    int cB1 = colidx[rsB + 8 + slot];
    int cB2 = 0, cB3 = 0;
    if (ctB > 16) { cB2 = colidx[rsB + 16 + slot]; cB3 = colidx[rsB + 24 + slot]; }

    // gathers for stage A
    G5 g = issue_gather(S, cA0, cA1, cA2, cA3, ctA, nA, slot, fp);

    int curg = bgA;
    float p0 = 0.f, p1 = 0.f;

    for (int t = 0; t < CHUNK / 4; ++t) {
        int nt = base + t * 4;                     // current node (consume stage)
        // --- issue gathers for nt+4 (colidx cB* arrived) ---
        G5 gn = issue_gather(S, cB0, cB1, cB2, cB3, ctB, cl(nt + 4), slot, fp);
        // --- issue meta for nt+12 ---
        int n3 = cl(nt + 12);
        int rsD = rowptr[n3], ctD = cnt[n3];
        float dvD = dinv[n3];
        int bgD = POOL ? batch[n3] : 0;
        // --- issue colidx for nt+8 (meta rsC/ctC arrived) ---
        int cC0 = colidx[rsC + slot];
        int cC1 = colidx[rsC + 8 + slot];
        int cC2 = 0, cC3 = 0;
        if (ctC > 16) { cC2 = colidx[rsC + 16 + slot]; cC3 = colidx[rsC + 24 + slot]; }
        // --- consume gathers for nt ---
        __half2 acc = __hadd2(__hadd2(h2(g.w0), h2(g.w1)), __hadd2(h2(g.w2), h2(g.w3)));
        if (ctA > 32) {                            // rare (~3e-5 of nodes)
            int nc = cl(nt);
            int e = rsA + ctA;
            for (int i = rsA + 32; i < e; i += 8) {
                int cc = colidx[i + slot];
                bool ok = (i + slot) < e;
                int ii = ok ? cc : nc;
                unsigned ww = S[(size_t)ii * 8 + fp];
                acc = __hadd2(acc, h2(ok ? ww : 0u));
            }
        }
        acc = __hadd2(acc, h2(__shfl_xor(uh(acc), 8, 64)));
        acc = __hadd2(acc, h2(__shfl_xor(uh(acc), 16, 64)));
        acc = __hadd2(acc, h2(__shfl_xor(uh(acc), 32, 64)));
        float2 av = __half22float2(acc);
        float2 sf = __half22float2(h2(g.sv));
        float r0 = fmaxf(fmaf(av.x + sf.x, dvA, b0), 0.f);
        float r1 = fmaxf(fmaf(av.y + sf.y, dvA, b1), 0.f);
        if (POOL) {
            if (bgA != curg) {                     // wave-uniform (batch sorted)
                if (lane < 8) {
                    float* p = &((float*)outp)[((size_t)s * NG + curg) * 16 + fp * 2];
                    atomicAdd(p + 0, p0);
                    atomicAdd(p + 1, p1);
                }
                curg = bgA; p0 = 0.f; p1 = 0.f;
            }
            if (nt < n) { p0 += r0; p1 += r1; }
        } else if (lane < 8 && nt < n) {
            ((unsigned*)outp)[((size_t)s * NN + nt) * 8 + fp] = pack_f16x2(r0, r1);
        }
        // --- rotate pipeline ---
        rsA = rsB; ctA = ctB; dvA = dvB; bgA = bgB;
        rsB = rsC; ctB = ctC; dvB = dvC; bgB = bgC;
        rsC = rsD; ctC = ctD; dvC = dvD; bgC = bgD;
        cB0 = cC0; cB1 = cC1; cB2 = cC2; cB3 = cC3;
        g = gn;
    }
    if (POOL && lane < 8) {                        // final flush
        float* p = &((float*)outp)[((size_t)s * NG + curg) * 16 + fp * 2];
        atomicAdd(p + 0, p0);
        atomicAdd(p + 1, p1);
    }
}

// out[g][o] = (sum_f pool_s[f/16][g][f%16]/cnt[g] * Wfc[f][o]) + bfc[o]; wave/graph
__global__ void k_final(const float* __restrict__ pool, const int* __restrict__ pcnt,
                        const float* __restrict__ Wfc, const float* __restrict__ bfc,
                        float* __restrict__ out, int ng) {
    int tid = threadIdx.x;
    int wave = tid >> 6, lane = tid & 63;
    int g = blockIdx.x * 4 + wave;
    if (g >= ng) return;
    float inv = 1.0f / fmaxf((float)pcnt[g], 1.0f);
    float s = pool[((size_t)(lane >> 4) * NG + g) * 16 + (lane & 15)] * inv;
    float a0 = s * Wfc[lane * 2 + 0];
    float a1 = s * Wfc[lane * 2 + 1];
#pragma unroll
    for (int off = 32; off > 0; off >>= 1) {
        a0 += __shfl_down(a0, off, 64);
        a1 += __shfl_down(a1, off, 64);
    }
    if (lane == 0) {
        out[g * 2 + 0] = a0 + bfc[0];
        out[g * 2 + 1] = a1 + bfc[1];
    }
}

extern "C" void kernel_launch(void* const* d_in, const int* in_sizes, int n_in,
                              void* d_out, int out_size, void* d_ws, size_t ws_size,
                              hipStream_t stream) {
    const float* x    = (const float*)d_in[0];
    const int*   eidx = (const int*)d_in[1];   // [2][NE]: row0 = src, row1 = dst
    const int*   batch= (const int*)d_in[2];
    const float* W1   = (const float*)d_in[3];
    const float* b1   = (const float*)d_in[4];
    const float* W2   = (const float*)d_in[5];
    const float* b2   = (const float*)d_in[6];
    const float* Wfc  = (const float*)d_in[7];
    const float* bfc  = (const float*)d_in[8];
    float* out = (float*)d_out;

    const int* esrc = eidx;
    const int* edst = eidx + NE;

    char* ws = (char*)d_ws;
    size_t off = 0;
    auto alloc = [&](size_t bytes) {
        char* p = ws + off;
        off += (bytes + 255) & ~(size_t)255;
        return p;
    };
    int*      cnt      = (int*)     alloc(NN * 4);
    int*      rowptr   = (int*)     alloc(NN * 4);
    int*      blockSum = (int*)     alloc(128 * 4);
    int*      blockOff = (int*)     alloc(128 * 4);
    float*    dinv     = (float*)   alloc(NN * 4);
    int*      colidx   = (int*)     alloc((size_t)(NE + 64) * 4);  // +pad for slot overreach
    unsigned* hs       = (unsigned*)alloc((size_t)NN * FD * 2);    // fp16 sliced [4][NN][16]
    unsigned* h1       = (unsigned*)alloc((size_t)NN * FD * 2);    // fp16 sliced [4][NN][16]
    float*    pool     = (float*)   alloc((size_t)NSL * NG * 16 * 4);  // sliced [4][NG][16]
    int*      pcnt     = (int*)     alloc(NG * 4);
    // rank aliases h1 (rank last used in k_fill, h1 first written by k_agg4<0>)
    int*      rank     = (int*)h1;
    (void)ws_size;

    hipMemsetAsync(cnt,  0, NN * 4, stream);
    hipMemsetAsync(pool, 0, (size_t)NSL * NG * 16 * 4, stream);

    const int GE = (NE + 255) / 256;   // 6250
    const int GN = (NN + 255) / 256;   // 391
    const int GR = (NN + 15) / 16;     // gemm: 16 rows/block
    const int GA = ((NN + CHUNK - 1) / CHUNK) * NSL;   // 782*4 = 3128

    k_count_rank<<<GE, 256, 0, stream>>>(edst, cnt, rank, NE);
    k_scan1<<<SCAN_BLOCKS, 256, 0, stream>>>(cnt, rowptr, blockSum, NN);
    k_scan2<<<1, 128, 0, stream>>>(blockSum, blockOff, SCAN_BLOCKS);
    k_scan3<<<GN, 256, 0, stream>>>(rowptr, blockOff, cnt, dinv, NN);
    k_pcnt_bs<<<2, 256, 0, stream>>>(batch, pcnt, NN, NG);
    k_fill<<<GE, 256, 0, stream>>>(esrc, edst, rank, rowptr, colidx, NE);

    // layer 1: hs = f16_sliced((x @ W1) * dinv); h1 = f16_sliced(relu(...))
    k_gemm_scale<0><<<GR, 256, 0, stream>>>(x, W1, dinv, hs, NN);
    k_agg4<0><<<GA, 256, 0, stream>>>(hs, rowptr, cnt, colidx, dinv, b1, batch, h1, NN);

    // layer 2: hs = f16_sliced((h1 @ W2) * dinv); pool += relu(...)
    k_gemm_scale<1><<<GR, 256, 0, stream>>>(h1, W2, dinv, hs, NN);
    k_agg4<1><<<GA, 256, 0, stream>>>(hs, rowptr, cnt, colidx, dinv, b2, batch, pool, NN);

    // readout
    k_final<<<(NG + 3) / 4, 256, 0, stream>>>(pool, pcnt, Wfc, bfc, out, NG);
}

// Round 13
// 351.512 us; speedup vs baseline: 1.2097x; 1.0325x over previous
//
#include <hip/hip_runtime.h>
#include <hip/hip_fp16.h>

// TargetModel_78786880077968: 2-layer GCN + mean pool
#define NN 100000      // nodes
#define NE 1600000     // edges
#define NG 512         // graphs
#define FD 64          // feature dim
#define NSL 4          // feature slices (XCD-pinned); 16 fp16 each = 32 B rows
#define SR (NN + 1)    // hs slice row stride; row NN = zeros (pad target)
#define CHUNK 128      // nodes per agg block
#define SCAN_CHUNK 1024
#define SCAN_BLOCKS 98  // ceil(NN / SCAN_CHUNK)

// ---- fp16 pack/unpack ----
union U32H2 { unsigned u; __half2 h; };
__device__ inline __half2 h2(unsigned v) { U32H2 c; c.u = v; return c.h; }
__device__ inline unsigned uh(__half2 v) { U32H2 c; c.h = v; return c.u; }
__device__ inline unsigned pack_f16x2(float a, float b) {
    return uh(__floats2half2_rn(a, b));
}

// ---------- CSR build ----------

__global__ void k_count_rank(const int* __restrict__ dst, int* __restrict__ cnt,
                             int* __restrict__ rank, int e) {
    int i = blockIdx.x * 256 + threadIdx.x;
    if (i < e) rank[i] = atomicAdd(&cnt[dst[i]], 1);
}

__global__ void k_scan1(const int* __restrict__ cnt, int* __restrict__ part,
                        int* __restrict__ blockSum, int n) {
    __shared__ int lds[256];
    int tid = threadIdx.x;
    int base = blockIdx.x * SCAN_CHUNK + tid * 4;
    int v0 = (base + 0 < n) ? cnt[base + 0] : 0;
    int v1 = (base + 1 < n) ? cnt[base + 1] : 0;
    int v2 = (base + 2 < n) ? cnt[base + 2] : 0;
    int v3 = (base + 3 < n) ? cnt[base + 3] : 0;
    int s = v0 + v1 + v2 + v3;
    lds[tid] = s;
    __syncthreads();
    for (int off = 1; off < 256; off <<= 1) {
        int t = (tid >= off) ? lds[tid - off] : 0;
        __syncthreads();
        lds[tid] += t;
        __syncthreads();
    }
    int run = lds[tid] - s;
    if (base + 0 < n) part[base + 0] = run; run += v0;
    if (base + 1 < n) part[base + 1] = run; run += v1;
    if (base + 2 < n) part[base + 2] = run; run += v2;
    if (base + 3 < n) part[base + 3] = run;
    if (tid == 255) blockSum[blockIdx.x] = lds[255];
}

// scan of block sums + zero-row init for hs slices (idle lanes)
__global__ void k_scan2(const int* __restrict__ bs, int* __restrict__ boff, int nb,
                        unsigned* __restrict__ hs) {
    __shared__ int lds[128];
    int tid = threadIdx.x;
    if (tid < 32)   // zero row NN of each of the 4 slices (8 dwords each)
        hs[(size_t)(tid >> 3) * SR * 8 + (size_t)NN * 8 + (tid & 7)] = 0u;
    int v = (tid < nb) ? bs[tid] : 0;
    lds[tid] = v;
    __syncthreads();
    for (int off = 1; off < 128; off <<= 1) {
        int t = (tid >= off) ? lds[tid - off] : 0;
        __syncthreads();
        lds[tid] += t;
        __syncthreads();
    }
    if (tid < nb) boff[tid] = lds[tid] - v;
}

__global__ void k_scan3(int* __restrict__ rowptr, const int* __restrict__ boff,
                        const int* __restrict__ cnt, float* __restrict__ dinv, int n) {
    int i = blockIdx.x * 256 + threadIdx.x;
    if (i < n) {
        rowptr[i] = rowptr[i] + boff[i >> 10];
        float deg = (float)(cnt[i] + 1);  // +1 self loop
        dinv[i] = 1.0f / sqrtf(deg);
    }
}

// per-graph node counts via binary search over sorted batch (no atomics)
__global__ void k_pcnt_bs(const int* __restrict__ batch, int* __restrict__ pcnt, int n, int ng) {
    int g = blockIdx.x * 256 + threadIdx.x;
    if (g >= ng) return;
    int lo = 0, hi = n;
    while (lo < hi) { int m = (lo + hi) >> 1; if (batch[m] < g) lo = m + 1; else hi = m; }
    int l0 = lo;
    lo = 0; hi = n;
    int v = g + 1;
    while (lo < hi) { int m = (lo + hi) >> 1; if (batch[m] < v) lo = m + 1; else hi = m; }
    pcnt[g] = lo - l0;
}

__global__ void k_fill(const int* __restrict__ src, const int* __restrict__ dst,
                       const int* __restrict__ rank, const int* __restrict__ rowptr,
                       int* __restrict__ colidx, int e) {
    int i = blockIdx.x * 256 + threadIdx.x;
    if (i < e) {
        int d = dst[i];
        colidx[rowptr[d] + rank[i]] = src[i];
    }
}

// ---------- dense GEMM, sliced fp16 in/out ----------
// hs[s][row][16 fp16] = f16( dinv[row] * sum_k in[row][k] * W[k][s*16 + j] )
template <int F16IN>
__global__ void k_gemm_scale(const void* __restrict__ inv_, const float* __restrict__ W,
                             const float* __restrict__ dinv, unsigned* __restrict__ hs, int n) {
    __shared__ float w[FD * FD];        // 16 KB
    __shared__ float xr[4][4][80];      // padded f32 row staging
    int tid = threadIdx.x;
    {
        const float4* W4 = (const float4*)W;
        float4* w4s = (float4*)w;
        for (int i = tid; i < FD * FD / 4; i += 256) w4s[i] = W4[i];
    }
    int wave = tid >> 6, lane = tid & 63;
    int r = lane >> 4;        // row within wave
    int c = lane & 15;        // 4-feature chunk
    int row = blockIdx.x * 16 + wave * 4 + r;
    bool valid = row < n;
    if (valid) {
        if (F16IN) {
            uint2 v = ((const uint2*)inv_)[(unsigned)((c >> 2) * NN + row) * 4u + (unsigned)(c & 3)];
            float2 f0 = __half22float2(h2(v.x));
            float2 f1 = __half22float2(h2(v.y));
            xr[wave][r][c * 4 + 0] = f0.x;
            xr[wave][r][c * 4 + 1] = f0.y;
            xr[wave][r][c * 4 + 2] = f1.x;
            xr[wave][r][c * 4 + 3] = f1.y;
        } else {
            float4 xv = ((const float4*)inv_)[(unsigned)row * 16u + (unsigned)c];
            *((float4*)&xr[wave][r][c * 4]) = xv;
        }
    }
    __syncthreads();
    if (!valid) return;
    const float4* w4 = (const float4*)w;
    float4 acc = {0.f, 0.f, 0.f, 0.f};
#pragma unroll
    for (int k = 0; k < FD; ++k) {
        float xv = xr[wave][r][k];
        float4 wv = w4[k * 16 + c];
        acc.x = fmaf(xv, wv.x, acc.x);
        acc.y = fmaf(xv, wv.y, acc.y);
        acc.z = fmaf(xv, wv.z, acc.z);
        acc.w = fmaf(xv, wv.w, acc.w);
    }
    float d = dinv[row];
    uint2 o;
    o.x = pack_f16x2(acc.x * d, acc.y * d);
    o.y = pack_f16x2(acc.z * d, acc.w * d);
    ((uint2*)hs)[(unsigned)((c >> 2) * SR + row) * 4u + (unsigned)(c & 3)] = o;
}

// ---- gather issue: clamp pad indices to zero-row NN; no result masks ----
struct G5 { unsigned w0, w1, w2, w3, sv; };
__device__ inline G5 issue_gather(const unsigned* __restrict__ S,
                                  int c0, int c1, int c2, int c3,
                                  int ct, int nc, int slot, unsigned fp) {
    G5 g;
    int i0 = (slot < ct) ? c0 : NN;
    int i1 = (slot + 8 < ct) ? c1 : NN;
    g.w0 = S[(unsigned)i0 * 8u + fp];
    g.w1 = S[(unsigned)i1 * 8u + fp];
    g.sv = S[(unsigned)nc * 8u + fp];
    if (ct > 16) {                      // wave-uniform branch
        int i2 = (slot + 16 < ct) ? c2 : NN;
        int i3 = (slot + 24 < ct) ? c3 : NN;
        g.w2 = S[(unsigned)i2 * 8u + fp];
        g.w3 = S[(unsigned)i3 * 8u + fp];
    } else { g.w2 = 0u; g.w3 = 0u; }
    return g;
}

// ---------- sliced aggregation, 3-stage decoupled pipeline, 32-bit addressing ----
template <int POOL>
__global__ void k_agg4(const unsigned* __restrict__ hs, const int* __restrict__ rowptr,
                       const int* __restrict__ cnt, const int* __restrict__ colidx,
                       const float* __restrict__ dinv, const float* __restrict__ b,
                       const int* __restrict__ batch, void* __restrict__ outp, int n) {
    int bid = blockIdx.x;
    int s = bid & 3;
    int chunk = bid >> 2;
    int tid = threadIdx.x;
    int wave = tid >> 6, lane = tid & 63;
    int slot = lane >> 3;
    unsigned fp = (unsigned)(lane & 7);
    const unsigned* S = hs + (size_t)s * SR * 8;   // 3.2 MB slice (8 dwords/row)
    float b0 = b[s * 16 + (int)fp * 2], b1 = b[s * 16 + (int)fp * 2 + 1];

    int base = chunk * CHUNK + wave;               // nodes: base + 4t, t in [0,32)
    auto cl = [n](int i) { return i < n ? i : n - 1; };

    // ---- prologue: fill 3 pipeline stages ----
    int nA = cl(base);
    int rsA = rowptr[nA], ctA = cnt[nA];
    float dvA = dinv[nA];
    int bgA = POOL ? batch[nA] : 0;
    int nB = cl(base + 4);
    int rsB = rowptr[nB], ctB = cnt[nB];
    float dvB = dinv[nB];
    int bgB = POOL ? batch[nB] : 0;
    int nC = cl(base + 8);
    int rsC = rowptr[nC], ctC = cnt[nC];
    float dvC = dinv[nC];
    int bgC = POOL ? batch[nC] : 0;

    int cA0 = colidx[(unsigned)(rsA + slot)];
    int cA1 = colidx[(unsigned)(rsA + 8 + slot)];
    int cA2 = 0, cA3 = 0;
    if (ctA > 16) { cA2 = colidx[(unsigned)(rsA + 16 + slot)]; cA3 = colidx[(unsigned)(rsA + 24 + slot)]; }
    int cB0 = colidx[(unsigned)(rsB + slot)];
    int cB1 = colidx[(unsigned)(rsB + 8 + slot)];
    int cB2 = 0, cB3 = 0;
    if (ctB > 16) { cB2 = colidx[(unsigned)(rsB + 16 + slot)]; cB3 = colidx[(unsigned)(rsB + 24 + slot)]; }

    G5 g = issue_gather(S, cA0, cA1, cA2, cA3, ctA, nA, slot, fp);

    int curg = bgA;
    float p0 = 0.f, p1 = 0.f;

    for (int t = 0; t < CHUNK / 4; ++t) {
        int nt = base + t * 4;                     // current node (consume stage)
        // --- issue gathers for nt+4 ---
        G5 gn = issue_gather(S, cB0, cB1, cB2, cB3, ctB, cl(nt + 4), slot, fp);
        // --- issue meta for nt+12 ---
        int n3 = cl(nt + 12);
        int rsD = rowptr[n3], ctD = cnt[n3];
        float dvD = dinv[n3];
        int bgD = POOL ? batch[n3] : 0;
        // --- issue colidx for nt+8 ---
        int cC0 = colidx[(unsigned)(rsC + slot)];
        int cC1 = colidx[(unsigned)(rsC + 8 + slot)];
        int cC2 = 0, cC3 = 0;
        if (ctC > 16) { cC2 = colidx[(unsigned)(rsC + 16 + slot)]; cC3 = colidx[(unsigned)(rsC + 24 + slot)]; }
        // --- consume gathers for nt ---
        __half2 acc = __hadd2(__hadd2(h2(g.w0), h2(g.w1)), __hadd2(h2(g.w2), h2(g.w3)));
        if (ctA > 32) {                            // rare
            int e = rsA + ctA;
            for (int i = rsA + 32; i < e; i += 8) {
                int cc = colidx[(unsigned)(i + slot)];
                int ii = ((i + slot) < e) ? cc : NN;
                acc = __hadd2(acc, h2(S[(unsigned)ii * 8u + fp]));
            }
        }
        acc = __hadd2(acc, h2(__shfl_xor(uh(acc), 8, 64)));
        acc = __hadd2(acc, h2(__shfl_xor(uh(acc), 16, 64)));
        acc = __hadd2(acc, h2(__shfl_xor(uh(acc), 32, 64)));
        float2 av = __half22float2(acc);
        float2 sf = __half22float2(h2(g.sv));
        float r0 = fmaxf(fmaf(av.x + sf.x, dvA, b0), 0.f);
        float r1 = fmaxf(fmaf(av.y + sf.y, dvA, b1), 0.f);
        if (POOL) {
            if (bgA != curg) {                     // wave-uniform (batch sorted)
                if (lane < 8) {
                    float* p = &((float*)outp)[(unsigned)((s * NG + curg) * 16) + fp * 2u];
                    atomicAdd(p + 0, p0);
                    atomicAdd(p + 1, p1);
                }
                curg = bgA; p0 = 0.f; p1 = 0.f;
            }
            if (nt < n) { p0 += r0; p1 += r1; }
        } else if (lane < 8 && nt < n) {
            ((unsigned*)outp)[(unsigned)(s * NN + nt) * 8u + fp] = pack_f16x2(r0, r1);
        }
        // --- rotate pipeline ---
        rsA = rsB; ctA = ctB; dvA = dvB; bgA = bgB;
        rsB = rsC; ctB = ctC; dvB = dvC; bgB = bgC;
        rsC = rsD; ctC = ctD; dvC = dvD; bgC = bgD;
        cB0 = cC0; cB1 = cC1; cB2 = cC2; cB3 = cC3;
        g = gn;
    }
    if (POOL && lane < 8) {                        // final flush
        float* p = &((float*)outp)[(unsigned)((s * NG + curg) * 16) + fp * 2u];
        atomicAdd(p + 0, p0);
        atomicAdd(p + 1, p1);
    }
}

// out[g][o] = (sum_f pool_s[f/16][g][f%16]/cnt[g] * Wfc[f][o]) + bfc[o]; wave/graph
__global__ void k_final(const float* __restrict__ pool, const int* __restrict__ pcnt,
                        const float* __restrict__ Wfc, const float* __restrict__ bfc,
                        float* __restrict__ out, int ng) {
    int tid = threadIdx.x;
    int wave = tid >> 6, lane = tid & 63;
    int g = blockIdx.x * 4 + wave;
    if (g >= ng) return;
    float inv = 1.0f / fmaxf((float)pcnt[g], 1.0f);
    float s = pool[((size_t)(lane >> 4) * NG + g) * 16 + (lane & 15)] * inv;
    float a0 = s * Wfc[lane * 2 + 0];
    float a1 = s * Wfc[lane * 2 + 1];
#pragma unroll
    for (int off = 32; off > 0; off >>= 1) {
        a0 += __shfl_down(a0, off, 64);
        a1 += __shfl_down(a1, off, 64);
    }
    if (lane == 0) {
        out[g * 2 + 0] = a0 + bfc[0];
        out[g * 2 + 1] = a1 + bfc[1];
    }
}

extern "C" void kernel_launch(void* const* d_in, const int* in_sizes, int n_in,
                              void* d_out, int out_size, void* d_ws, size_t ws_size,
                              hipStream_t stream) {
    const float* x    = (const float*)d_in[0];
    const int*   eidx = (const int*)d_in[1];   // [2][NE]: row0 = src, row1 = dst
    const int*   batch= (const int*)d_in[2];
    const float* W1   = (const float*)d_in[3];
    const float* b1   = (const float*)d_in[4];
    const float* W2   = (const float*)d_in[5];
    const float* b2   = (const float*)d_in[6];
    const float* Wfc  = (const float*)d_in[7];
    const float* bfc  = (const float*)d_in[8];
    float* out = (float*)d_out;

    const int* esrc = eidx;
    const int* edst = eidx + NE;

    char* ws = (char*)d_ws;
    size_t off = 0;
    auto alloc = [&](size_t bytes) {
        char* p = ws + off;
        off += (bytes + 255) & ~(size_t)255;
        return p;
    };
    int*      cnt      = (int*)     alloc(NN * 4);
    int*      rowptr   = (int*)     alloc(NN * 4);
    int*      blockSum = (int*)     alloc(128 * 4);
    int*      blockOff = (int*)     alloc(128 * 4);
    float*    dinv     = (float*)   alloc(NN * 4);
    int*      colidx   = (int*)     alloc((size_t)(NE + 64) * 4);  // +pad for slot overreach
    unsigned* hs       = (unsigned*)alloc((size_t)SR * FD * 2);    // fp16 sliced [4][SR][16]
    unsigned* h1       = (unsigned*)alloc((size_t)NN * FD * 2);    // fp16 sliced [4][NN][16]
    float*    pool     = (float*)   alloc((size_t)NSL * NG * 16 * 4);  // sliced [4][NG][16]
    int*      pcnt     = (int*)     alloc(NG * 4);
    // rank aliases h1 (rank last used in k_fill, h1 first written by k_agg4<0>)
    int*      rank     = (int*)h1;
    (void)ws_size;

    hipMemsetAsync(cnt,  0, NN * 4, stream);
    hipMemsetAsync(pool, 0, (size_t)NSL * NG * 16 * 4, stream);

    const int GE = (NE + 255) / 256;   // 6250
    const int GN = (NN + 255) / 256;   // 391
    const int GR = (NN + 15) / 16;     // gemm: 16 rows/block
    const int GA = ((NN + CHUNK - 1) / CHUNK) * NSL;   // 782*4 = 3128

    k_count_rank<<<GE, 256, 0, stream>>>(edst, cnt, rank, NE);
    k_scan1<<<SCAN_BLOCKS, 256, 0, stream>>>(cnt, rowptr, blockSum, NN);
    k_scan2<<<1, 128, 0, stream>>>(blockSum, blockOff, SCAN_BLOCKS, hs);
    k_scan3<<<GN, 256, 0, stream>>>(rowptr, blockOff, cnt, dinv, NN);
    k_pcnt_bs<<<2, 256, 0, stream>>>(batch, pcnt, NN, NG);
    k_fill<<<GE, 256, 0, stream>>>(esrc, edst, rank, rowptr, colidx, NE);

    // layer 1: hs = f16_sliced((x @ W1) * dinv); h1 = f16_sliced(relu(...))
    k_gemm_scale<0><<<GR, 256, 0, stream>>>(x, W1, dinv, hs, NN);
    k_agg4<0><<<GA, 256, 0, stream>>>(hs, rowptr, cnt, colidx, dinv, b1, batch, h1, NN);

    // layer 2: hs = f16_sliced((h1 @ W2) * dinv); pool += relu(...)
    k_gemm_scale<1><<<GR, 256, 0, stream>>>(h1, W2, dinv, hs, NN);
    k_agg4<1><<<GA, 256, 0, stream>>>(hs, rowptr, cnt, colidx, dinv, b2, batch, pool, NN);

    // readout
    k_final<<<(NG + 3) / 4, 256, 0, stream>>>(pool, pcnt, Wfc, bfc, out, NG);
}